// Round 4
// baseline (1584.819 us; speedup 1.0000x reference)
//
#include <hip/hip_runtime.h>
#include <cstdint>

typedef __bf16 bf16_t;
typedef __bf16 bf16x2 __attribute__((ext_vector_type(2)));
typedef __bf16 bf16x4 __attribute__((ext_vector_type(4)));
typedef __bf16 bf16x8 __attribute__((ext_vector_type(8)));
typedef float f32x4 __attribute__((ext_vector_type(4)));

#define DEVI static __device__ __forceinline__

// async global->LDS, 16B per lane; LDS dest = wave-uniform base + lane*16
DEVI void g2l16(const void* g, void* l) {
  __builtin_amdgcn_global_load_lds((__attribute__((address_space(1))) void*)g,
                                   (__attribute__((address_space(3))) void*)l,
                                   16, 0, 0);
}

// ---------------- fused f32 -> bf16 convert (all tensors, one launch) ----------------
struct F2BArgs {
  const float* s[10];
  bf16_t* d[10];
  int n4[10];
};
__global__ void k_f2b_all(F2BArgs a) {
  const int seg = blockIdx.y;
  const float* __restrict__ in = a.s[seg];
  bf16_t* __restrict__ out = a.d[seg];
  const long n4 = a.n4[seg];
  const long stride = (long)gridDim.x * blockDim.x;
  for (long i = (long)blockIdx.x * blockDim.x + threadIdx.x; i < n4; i += stride) {
    float4 v = ((const float4*)in)[i];
    bf16x4 o = {(bf16_t)v.x, (bf16_t)v.y, (bf16_t)v.z, (bf16_t)v.w};
    ((bf16x4*)out)[i] = o;
  }
}

// ---------------- embedding ----------------
__global__ void k_embed(const int* __restrict__ ids, const float* __restrict__ tok,
                        const float* __restrict__ pos, float* __restrict__ x,
                        bf16_t* __restrict__ xb) {
  int r = blockIdx.x;
  int t = r & 2047;
  long id = ids[r];
  int d = threadIdx.x * 2;
  float2 a = *(const float2*)(tok + id * 512 + d);
  float2 p = *(const float2*)(pos + (long)t * 512 + d);
  float o0 = a.x + p.x, o1 = a.y + p.y;
  *(float2*)(x + (long)r * 512 + d) = make_float2(o0, o1);
  bf16x2 ob = {(bf16_t)o0, (bf16_t)o1};
  *(bf16x2*)(xb + (long)r * 512 + d) = ob;
}

DEVI float gelu_f(float f) {
  return 0.5f * f * (1.0f + erff(f * 0.70710678118654752f));
}

// ---------------- 128x128 GEMM: C[M,N] = (A[M,K] @ B[N,K]^T + bias) * alpha ----------------
// EPI: 1 = qkv split (q*0.125->qh, k->kh, v->vt), 2 = gelu -> C(bf16)
template <typename CT, bool BIAS, int EPI>
__global__ __launch_bounds__(256, 2) void k_gemm_bt(
    const bf16_t* __restrict__ A, int lda, const bf16_t* __restrict__ B, int ldb,
    CT* __restrict__ C, int ldc, const float* __restrict__ bias, int K, float alpha,
    bf16_t* __restrict__ qh, bf16_t* __restrict__ kh, bf16_t* __restrict__ vt) {
  __shared__ bf16_t As[4096];  // [128][32]
  __shared__ bf16_t Bs[4096];  // [128][32]
  const int tid = threadIdx.x;
  const int lane = tid & 63;
  const int w = tid >> 6;
  const int wm = w >> 1, wn = w & 1;
  const int m0 = blockIdx.y * 128;
  const int n0 = blockIdx.x * 128;

  f32x4 acc[4][4];
#pragma unroll
  for (int m = 0; m < 4; ++m)
#pragma unroll
    for (int n = 0; n < 4; ++n) acc[m][n] = (f32x4){0.f, 0.f, 0.f, 0.f};

  const int srow = tid >> 2;
  const int scol = (tid & 3) * 8;
  const int fr = lane & 15;
  const int g4 = lane >> 4;
  const int kg = g4 * 8;

  for (int k0 = 0; k0 < K; k0 += 32) {
#pragma unroll
    for (int p = 0; p < 2; ++p) {
      g2l16(A + (long long)(m0 + p * 64 + srow) * lda + (k0 + scol), As + p * 2048 + w * 512);
      g2l16(B + (long long)(n0 + p * 64 + srow) * ldb + (k0 + scol), Bs + p * 2048 + w * 512);
    }
    __syncthreads();
    bf16x8 fa[4], fb[4];
#pragma unroll
    for (int m = 0; m < 4; ++m)
      fa[m] = *(const bf16x8*)(As + (wm * 64 + m * 16 + fr) * 32 + kg);
#pragma unroll
    for (int n = 0; n < 4; ++n)
      fb[n] = *(const bf16x8*)(Bs + (wn * 64 + n * 16 + fr) * 32 + kg);
#pragma unroll
    for (int m = 0; m < 4; ++m)
#pragma unroll
      for (int n = 0; n < 4; ++n)
        acc[m][n] = __builtin_amdgcn_mfma_f32_16x16x32_bf16(fa[m], fb[n], acc[m][n], 0, 0, 0);
    __syncthreads();
  }

#pragma unroll
  for (int n = 0; n < 4; ++n) {
    const int col = n0 + wn * 64 + n * 16 + fr;
    const float bv = BIAS ? bias[col] : 0.0f;
    if (EPI == 1) {
      const int reg = col >> 9;
      const int h = (col >> 6) & 7;
      const int hd = col & 63;
#pragma unroll
      for (int m = 0; m < 4; ++m) {
        const int rb = m0 + wm * 64 + m * 16 + g4 * 4;
#pragma unroll
        for (int r = 0; r < 4; ++r) {
          const int row = rb + r;
          const int b = row >> 11, t = row & 2047;
          const long long bh = (long long)b * 8 + h;
          float v = acc[m][n][r] + bv;
          if (reg == 0) qh[(bh * 2048 + t) * 64 + hd] = (bf16_t)(v * 0.125f);
          else if (reg == 1) kh[(bh * 2048 + t) * 64 + hd] = (bf16_t)v;
          else vt[(bh * 64 + hd) * 2048 + t] = (bf16_t)v;
        }
      }
    } else {
#pragma unroll
      for (int m = 0; m < 4; ++m) {
        const long long rb = m0 + wm * 64 + m * 16 + g4 * 4;
#pragma unroll
        for (int r = 0; r < 4; ++r) {
          float v = (acc[m][n][r] + bv) * alpha;
          if (EPI == 2) v = gelu_f(v);
          C[(rb + r) * (long long)ldc + col] = (CT)v;
        }
      }
    }
  }
}

// ---------------- N=512 GEMM with optional fused residual+LayerNorm ----------------
// Block: 16 rows x all 512 cols. 512 threads = 8 waves (wave wn covers cols wn*64..+63).
// LN=0: xbf = (acc + bias) * alpha (bf16).  LN=1: y = xin + acc + bias; LN -> xout(f32)+xbf.
// LN=2: like 1 but writes xbf only.
template <int LN>
__global__ __launch_bounds__(512, 1) void k_gemm_ln(
    const bf16_t* __restrict__ A, int lda, const bf16_t* __restrict__ B, int ldb, int K,
    const float* __restrict__ bias, const float* __restrict__ xin,
    const float* __restrict__ lns, const float* __restrict__ lnb,
    float* __restrict__ xout, bf16_t* __restrict__ xbf, float alpha) {
  __shared__ bf16_t As[16 * 32];    // 1KB
  __shared__ bf16_t Bs[512 * 32];   // 32KB
  __shared__ float redS[8][16];
  __shared__ float redQ[8][16];
  const int tid = threadIdx.x;
  const int lane = tid & 63;
  const int w = tid >> 6;     // wave id = wn (col group)
  const int fr = lane & 15;
  const int g4 = lane >> 4;
  const int kg = g4 * 8;
  const int row0 = blockIdx.x * 16;

  f32x4 acc[4];
#pragma unroll
  for (int n = 0; n < 4; ++n) acc[n] = (f32x4){0.f, 0.f, 0.f, 0.f};

  for (int k0 = 0; k0 < K; k0 += 32) {
    // B plane: 512 rows x 32 k (32KB) in 4 wave-uniform issues of 8KB
#pragma unroll
    for (int j = 0; j < 4; ++j)
      g2l16(B + (long long)(j * 128 + (tid >> 2)) * ldb + k0 + (tid & 3) * 8,
            Bs + j * 4096 + tid * 8);
    // A plane: 16 rows x 32 k (1KB), wave 0 only
    if (tid < 64)
      g2l16(A + (long long)(row0 + (tid >> 2)) * lda + k0 + (tid & 3) * 8, As + tid * 8);
    __syncthreads();
    bf16x8 fa = *(const bf16x8*)(As + fr * 32 + kg);
    bf16x8 fb[4];
#pragma unroll
    for (int n = 0; n < 4; ++n)
      fb[n] = *(const bf16x8*)(Bs + (w * 64 + n * 16 + fr) * 32 + kg);
#pragma unroll
    for (int n = 0; n < 4; ++n)
      acc[n] = __builtin_amdgcn_mfma_f32_16x16x32_bf16(fa, fb[n], acc[n], 0, 0, 0);
    __syncthreads();
  }

  // epilogue
  int col[4];
  float bv[4];
#pragma unroll
  for (int n = 0; n < 4; ++n) {
    col[n] = w * 64 + n * 16 + fr;
    bv[n] = bias ? bias[col[n]] : 0.0f;
  }

  if (LN == 0) {
#pragma unroll
    for (int n = 0; n < 4; ++n)
#pragma unroll
      for (int r = 0; r < 4; ++r) {
        const long long row = row0 + g4 * 4 + r;
        xbf[row * 512 + col[n]] = (bf16_t)((acc[n][r] + bv[n]) * alpha);
      }
    return;
  }

  // y = xin + acc + bias (overwrite acc with y)
#pragma unroll
  for (int n = 0; n < 4; ++n)
#pragma unroll
    for (int r = 0; r < 4; ++r) {
      const long long row = row0 + g4 * 4 + r;
      acc[n][r] = xin[row * 512 + col[n]] + acc[n][r] + bv[n];
    }
  // per-row stats: reduce over n (in-lane) then fr (16 lanes) then 8 waves (LDS)
#pragma unroll
  for (int r = 0; r < 4; ++r) {
    float s = acc[0][r] + acc[1][r] + acc[2][r] + acc[3][r];
    float q = acc[0][r] * acc[0][r] + acc[1][r] * acc[1][r] + acc[2][r] * acc[2][r] +
              acc[3][r] * acc[3][r];
#pragma unroll
    for (int m = 1; m < 16; m <<= 1) { s += __shfl_xor(s, m); q += __shfl_xor(q, m); }
    if (fr == 0) { redS[w][g4 * 4 + r] = s; redQ[w][g4 * 4 + r] = q; }
  }
  __syncthreads();
#pragma unroll
  for (int r = 0; r < 4; ++r) {
    const int lrow = g4 * 4 + r;
    float S = 0.f, Q = 0.f;
#pragma unroll
    for (int ww = 0; ww < 8; ++ww) { S += redS[ww][lrow]; Q += redQ[ww][lrow]; }
    const float mean = S * (1.0f / 512.0f);
    const float var = Q * (1.0f / 512.0f) - mean * mean;
    const float rstd = rsqrtf(var + 1e-5f);
    const long long row = row0 + lrow;
#pragma unroll
    for (int n = 0; n < 4; ++n) {
      float o = (acc[n][r] - mean) * rstd * lns[col[n]] + lnb[col[n]];
      xbf[row * 512 + col[n]] = (bf16_t)o;
      if (LN == 1) xout[row * 512 + col[n]] = o;
    }
  }
}

// ---------------- 256x256 GEMM, BK=64, 8 waves, counted-vmcnt 2-phase pipeline ----------------
template <typename CT>
__global__ __launch_bounds__(512, 2) void k_gemm256(
    const bf16_t* __restrict__ A, int lda, const bf16_t* __restrict__ B, int ldb,
    CT* __restrict__ C, int ldc, int K, float alpha) {
  __shared__ char lds[131072];
  const int tid = threadIdx.x;
  const int lane = tid & 63;
  const int w = tid >> 6;
  const int wm = w >> 2, wn = w & 3;
  const int fr = lane & 15;
  const int g4 = lane >> 4;

  int nwg = gridDim.x * gridDim.y;
  int lin = blockIdx.y * gridDim.x + blockIdx.x;
  if ((nwg & 7) == 0) lin = (lin & 7) * (nwg >> 3) + (lin >> 3);
  const int m0 = (lin / gridDim.x) * 256;
  const int n0 = (lin % gridDim.x) * 256;

  f32x4 acc[8][4];
#pragma unroll
  for (int m = 0; m < 8; ++m)
#pragma unroll
    for (int n = 0; n < 4; ++n) acc[m][n] = (f32x4){0.f, 0.f, 0.f, 0.f};

  const int sr = tid >> 2;
  const int sc = (tid & 3) * 16;
  const int NT = K >> 6;

  auto stage = [&](int t, int p, int buf) {
    const long long kb = (long long)t * 128 + p * 64;
    char* ab = (char*)lds + buf * 65536 + p * 16384;
    char* bb = ab + 32768;
    const int sw = (sr & 3) << 4;
    g2l16((const char*)A + (long long)(m0 + sr) * (lda * 2) + kb + (sc ^ sw), ab + tid * 16);
    g2l16((const char*)A + (long long)(m0 + 128 + sr) * (lda * 2) + kb + (sc ^ sw),
          ab + (tid + 512) * 16);
    g2l16((const char*)B + (long long)(n0 + sr) * (ldb * 2) + kb + (sc ^ sw), bb + tid * 16);
    g2l16((const char*)B + (long long)(n0 + 128 + sr) * (ldb * 2) + kb + (sc ^ sw),
          bb + (tid + 512) * 16);
  };

  stage(0, 0, 0);
  stage(0, 1, 0);
  asm volatile("s_waitcnt vmcnt(4)" ::: "memory");
  __builtin_amdgcn_s_barrier();
  __builtin_amdgcn_sched_barrier(0);

  int cur = 0;
  for (int t = 0; t < NT; ++t) {
#pragma unroll
    for (int p = 0; p < 2; ++p) {
      const char* ab = (const char*)lds + cur * 65536 + p * 16384;
      const char* bb = ab + 32768;
      bf16x8 fa[8], fb[4];
#pragma unroll
      for (int m = 0; m < 8; ++m) {
        const int row = wm * 128 + m * 16 + fr;
        fa[m] = *(const bf16x8*)(ab + row * 64 + ((g4 * 16) ^ ((row & 3) << 4)));
      }
#pragma unroll
      for (int n = 0; n < 4; ++n) {
        const int row = wn * 64 + n * 16 + fr;
        fb[n] = *(const bf16x8*)(bb + row * 64 + ((g4 * 16) ^ ((row & 3) << 4)));
      }
      if (t + 1 < NT) stage(t + 1, p, cur ^ 1);
      if (t == NT - 1 && p == 0) {
        asm volatile("s_waitcnt vmcnt(0)" ::: "memory");
      } else {
        asm volatile("s_waitcnt vmcnt(4)" ::: "memory");
      }
      __builtin_amdgcn_s_barrier();
      __builtin_amdgcn_sched_barrier(0);
      __builtin_amdgcn_s_setprio(1);
#pragma unroll
      for (int m = 0; m < 8; ++m)
#pragma unroll
        for (int n = 0; n < 4; ++n)
          acc[m][n] = __builtin_amdgcn_mfma_f32_16x16x32_bf16(fa[m], fb[n], acc[m][n], 0, 0, 0);
      __builtin_amdgcn_s_setprio(0);
    }
    cur ^= 1;
  }

#pragma unroll
  for (int n = 0; n < 4; ++n) {
    const int col = n0 + wn * 64 + n * 16 + fr;
#pragma unroll
    for (int m = 0; m < 8; ++m) {
      const long long rb = m0 + wm * 128 + m * 16 + g4 * 4;
#pragma unroll
      for (int r = 0; r < 4; ++r)
        C[(rb + r) * (long long)ldc + col] = (CT)(acc[m][n][r] * alpha);
    }
  }
}

// ---------------- fused flash attention ----------------
__global__ __launch_bounds__(256, 2) void k_flash(
    const bf16_t* __restrict__ qh, const bf16_t* __restrict__ kh,
    const bf16_t* __restrict__ vt, bf16_t* __restrict__ out) {
  __shared__ bf16_t Ks[128 * 64];
  __shared__ bf16_t Vs[64 * 128];
  __shared__ bf16_t Ps[4 * 32 * 128];
  const int tid = threadIdx.x;
  const int lane = tid & 63;
  const int w = tid >> 6;
  const int bh = blockIdx.y;
  const int q0 = blockIdx.x * 128;
  const int fr = lane & 15;
  const int g4 = lane >> 4;
  const int kg = g4 * 8;

  bf16x8 qf[2][2];
  {
    const bf16_t* qb = qh + ((long long)bh * 2048 + q0 + w * 32) * 64;
#pragma unroll
    for (int m = 0; m < 2; ++m)
#pragma unroll
      for (int ks = 0; ks < 2; ++ks)
        qf[m][ks] = *(const bf16x8*)(qb + (m * 16 + fr) * 64 + ks * 32 + kg);
  }

  f32x4 oacc[2][4];
#pragma unroll
  for (int m = 0; m < 2; ++m)
#pragma unroll
    for (int n = 0; n < 4; ++n) oacc[m][n] = (f32x4){0.f, 0.f, 0.f, 0.f};
  float mi[8], li[8];
#pragma unroll
  for (int j = 0; j < 8; ++j) { mi[j] = -1e30f; li[j] = 0.f; }

  char* PsW = (char*)(Ps + w * 32 * 128);
  const bf16_t* kbase = kh + (long long)bh * 2048 * 64;
  const bf16_t* vbase = vt + (long long)bh * 64 * 2048;

  for (int kt = 0; kt < 16; ++kt) {
#pragma unroll
    for (int i = 0; i < 4; ++i) {
      int row = (w * 4 + i) * 8 + (lane >> 3);
      int c = lane & 7;
      g2l16(kbase + ((long long)(kt * 128 + row)) * 64 + (c ^ (row & 7)) * 8,
            Ks + (w * 4 + i) * 512);
    }
#pragma unroll
    for (int i = 0; i < 4; ++i) {
      int d = w * 16 + i * 4 + (lane >> 4);
      int c = lane & 15;
      g2l16(vbase + (long long)d * 2048 + kt * 128 + ((c ^ (d & 7)) * 8),
            Vs + (w * 16 + i * 4) * 128);
    }
    __syncthreads();

    f32x4 s[2][8];
#pragma unroll
    for (int m = 0; m < 2; ++m)
#pragma unroll
      for (int n = 0; n < 8; ++n) s[m][n] = (f32x4){0.f, 0.f, 0.f, 0.f};
#pragma unroll
    for (int ks = 0; ks < 2; ++ks) {
#pragma unroll
      for (int n = 0; n < 8; ++n) {
        int row = n * 16 + fr;
        bf16x8 kf = *(const bf16x8*)((const char*)Ks + row * 128 +
                                     ((ks * 64 + kg * 2) ^ ((row & 7) << 4)));
#pragma unroll
        for (int m = 0; m < 2; ++m)
          s[m][n] = __builtin_amdgcn_mfma_f32_16x16x32_bf16(qf[m][ks], kf, s[m][n], 0, 0, 0);
      }
    }

#pragma unroll
    for (int m = 0; m < 2; ++m) {
#pragma unroll
      for (int r = 0; r < 4; ++r) {
        float pm = -1e30f;
#pragma unroll
        for (int n = 0; n < 8; ++n) pm = fmaxf(pm, s[m][n][r]);
        pm = fmaxf(pm, __shfl_xor(pm, 1));
        pm = fmaxf(pm, __shfl_xor(pm, 2));
        pm = fmaxf(pm, __shfl_xor(pm, 4));
        pm = fmaxf(pm, __shfl_xor(pm, 8));
        const int ri = m * 4 + r;
        const float mnew = fmaxf(mi[ri], pm);
        const float alpha = __expf(mi[ri] - mnew);
        mi[ri] = mnew;
        const int lr = m * 16 + g4 * 4 + r;
        const int sw = (lr & 7) << 4;
        float rs = 0.f;
#pragma unroll
        for (int n = 0; n < 8; ++n) {
          float p = __expf(s[m][n][r] - mnew);
          rs += p;
          *(bf16_t*)(PsW + lr * 256 + (((n * 16 + fr) * 2) ^ sw)) = (bf16_t)p;
        }
        rs += __shfl_xor(rs, 1);
        rs += __shfl_xor(rs, 2);
        rs += __shfl_xor(rs, 4);
        rs += __shfl_xor(rs, 8);
        li[ri] = li[ri] * alpha + rs;
#pragma unroll
        for (int n = 0; n < 4; ++n) oacc[m][n][r] *= alpha;
      }
    }

#pragma unroll
    for (int ks = 0; ks < 4; ++ks) {
      bf16x8 pa[2];
#pragma unroll
      for (int m = 0; m < 2; ++m) {
        int row = m * 16 + fr;
        pa[m] = *(const bf16x8*)(PsW + row * 256 + ((ks * 64 + kg * 2) ^ ((row & 7) << 4)));
      }
#pragma unroll
      for (int n = 0; n < 4; ++n) {
        int d = n * 16 + fr;
        bf16x8 vf = *(const bf16x8*)((const char*)Vs + d * 256 +
                                     ((ks * 64 + kg * 2) ^ ((d & 7) << 4)));
#pragma unroll
        for (int m = 0; m < 2; ++m)
          oacc[m][n] = __builtin_amdgcn_mfma_f32_16x16x32_bf16(pa[m], vf, oacc[m][n], 0, 0, 0);
      }
    }
    __syncthreads();
  }

  const int b = bh >> 3, h = bh & 7;
  bf16_t* ob = out + ((long long)b * 2048 + q0 + w * 32) * 512 + h * 64;
#pragma unroll
  for (int m = 0; m < 2; ++m)
#pragma unroll
    for (int r = 0; r < 4; ++r) {
      float inv = 1.0f / li[m * 4 + r];
#pragma unroll
      for (int n = 0; n < 4; ++n)
        ob[(m * 16 + g4 * 4 + r) * 512 + n * 16 + fr] = (bf16_t)(oacc[m][n][r] * inv);
    }
}

// ---------------- merged top-4 (3 levels in one launch) ----------------
DEVI bool tk_better(float av, int ai, float bv, int bi) {
  return (av > bv) || (av == bv && ai < bi);
}
DEVI void tk_insert(float* v, int* ix, float nv, int ni) {
  if (!tk_better(nv, ni, v[3], ix[3])) return;
  v[3] = nv; ix[3] = ni;
#pragma unroll
  for (int j = 3; j > 0; --j) {
    if (tk_better(v[j], ix[j], v[j - 1], ix[j - 1])) {
      float tv_ = v[j]; v[j] = v[j - 1]; v[j - 1] = tv_;
      int ti_ = ix[j]; ix[j] = ix[j - 1]; ix[j - 1] = ti_;
    }
  }
}
struct TopkArgs {
  const float* sal0; const float* sal1; const float* sal2;
};
__global__ void k_topk(const bf16_t* __restrict__ sc, TopkArgs a,
                       float* __restrict__ tv, int* __restrict__ ti) {
  const int lev = blockIdx.y;
  const int ncol = 16384 >> lev;
  const int coff = lev == 0 ? 0 : (lev == 1 ? 16384 : 24576);
  const float* sal = lev == 0 ? a.sal0 : (lev == 1 ? a.sal1 : a.sal2);
  const int r = blockIdx.x * 4 + (threadIdx.x >> 6);
  const int lane = threadIdx.x & 63;
  float v[4] = {-1e30f, -1e30f, -1e30f, -1e30f};
  int ix[4] = {0x7fffffff, 0x7fffffff, 0x7fffffff, 0x7fffffff};
  const bf16_t* row = sc + (long)r * 28672 + coff;
  for (int c0 = lane * 8; c0 < ncol; c0 += 512) {
    bf16x8 sv = *(const bf16x8*)(row + c0);
    float4 s0 = *(const float4*)(sal + c0);
    float4 s1 = *(const float4*)(sal + c0 + 4);
    tk_insert(v, ix, (float)sv[0] + s0.x, c0 + 0);
    tk_insert(v, ix, (float)sv[1] + s0.y, c0 + 1);
    tk_insert(v, ix, (float)sv[2] + s0.z, c0 + 2);
    tk_insert(v, ix, (float)sv[3] + s0.w, c0 + 3);
    tk_insert(v, ix, (float)sv[4] + s1.x, c0 + 4);
    tk_insert(v, ix, (float)sv[5] + s1.y, c0 + 5);
    tk_insert(v, ix, (float)sv[6] + s1.z, c0 + 6);
    tk_insert(v, ix, (float)sv[7] + s1.w, c0 + 7);
  }
#pragma unroll
  for (int dd = 1; dd < 64; dd <<= 1) {
    float ov[4]; int oi[4];
#pragma unroll
    for (int j = 0; j < 4; ++j) { ov[j] = __shfl_xor(v[j], dd); oi[j] = __shfl_xor(ix[j], dd); }
#pragma unroll
    for (int j = 0; j < 4; ++j) tk_insert(v, ix, ov[j], oi[j]);
  }
  if (lane == 0) {
    const long o = ((long)lev * 4096 + r) * 4;
#pragma unroll
    for (int j = 0; j < 4; ++j) { tv[o + j] = v[j]; ti[o + j] = ix[j]; }
  }
}

// ---------------- gather V by top-4, softmax weights, avg over 3 levels ----------------
__global__ void k_read(const float* __restrict__ tv, const int* __restrict__ ti,
                       const float* __restrict__ V0, const float* __restrict__ V1,
                       const float* __restrict__ V2, bf16_t* __restrict__ readb) {
  const int r = blockIdx.x;
  const int d = threadIdx.x * 2;
  float a0 = 0.f, a1 = 0.f;
  const float* Vs[3] = {V0, V1, V2};
#pragma unroll
  for (int lev = 0; lev < 3; ++lev) {
    const float* tvr = tv + ((long)lev * 4096 + r) * 4;
    const int* tir = ti + ((long)lev * 4096 + r) * 4;
    float t0 = tvr[0], t1 = tvr[1], t2 = tvr[2], t3 = tvr[3];
    float m = fmaxf(fmaxf(t0, t1), fmaxf(t2, t3));
    float e0 = __expf(t0 - m), e1 = __expf(t1 - m), e2 = __expf(t2 - m), e3 = __expf(t3 - m);
    float inv = 1.0f / (e0 + e1 + e2 + e3);
    float w4[4] = {e0 * inv, e1 * inv, e2 * inv, e3 * inv};
#pragma unroll
    for (int k = 0; k < 4; ++k) {
      const float* vr = Vs[lev] + (long)tir[k] * 512;
      a0 += w4[k] * vr[d];
      a1 += w4[k] * vr[d + 1];
    }
  }
  bf16x2 o = {(bf16_t)(a0 * (1.0f / 3.0f)), (bf16_t)(a1 * (1.0f / 3.0f))};
  *(bf16x2*)(readb + (long)r * 512 + d) = o;
}

// ---------------- host ----------------
extern "C" void kernel_launch(void* const* d_in, const int* in_sizes, int n_in,
                              void* d_out, int out_size, void* d_ws, size_t ws_size,
                              hipStream_t stream) {
  (void)in_sizes; (void)n_in; (void)out_size; (void)ws_size;
  const int* ids = (const int*)d_in[0];
  const float* tok = (const float*)d_in[1];
  const float* pos = (const float*)d_in[2];
  const float* Wqkv = (const float*)d_in[3];
  const float* bqkv = (const float*)d_in[4];
  const float* Wo = (const float*)d_in[5];
  const float* bo = (const float*)d_in[6];
  const float* ln1s = (const float*)d_in[7];
  const float* ln1b = (const float*)d_in[8];
  const float* W1 = (const float*)d_in[9];
  const float* b1 = (const float*)d_in[10];
  const float* W2 = (const float*)d_in[11];
  const float* b2 = (const float*)d_in[12];
  const float* ln2s = (const float*)d_in[13];
  const float* ln2b = (const float*)d_in[14];
  const float* Wq = (const float*)d_in[15];
  const float* bq = (const float*)d_in[16];
  const float* Wrp = (const float*)d_in[17];
  const float* brp = (const float*)d_in[18];
  const float* lnos = (const float*)d_in[19];
  const float* lnob = (const float*)d_in[20];
  const float* K0 = (const float*)d_in[21];
  const float* V0 = (const float*)d_in[22];
  const float* s0 = (const float*)d_in[23];
  const float* K1 = (const float*)d_in[24];
  const float* V1 = (const float*)d_in[25];
  const float* s1 = (const float*)d_in[26];
  const float* K2 = (const float*)d_in[27];
  const float* V2 = (const float*)d_in[28];
  const float* s2 = (const float*)d_in[29];

  char* wp = (char*)d_ws;
  auto walloc = [&](size_t bytes) -> char* {
    char* p = wp; wp += (bytes + 255) & ~(size_t)255; return p;
  };
  char* op = (char*)d_out;
  auto oalloc = [&](size_t bytes) -> char* {
    char* p = op; op += (bytes + 255) & ~(size_t)255; return p;
  };

  // transients in d_out (all reads complete before lm_head overwrites d_out)
  bf16_t* Wqkvb = (bf16_t*)oalloc(3145728ULL * 2);
  bf16_t* Wob   = (bf16_t*)oalloc(1048576ULL * 2);
  bf16_t* W1b   = (bf16_t*)oalloc(4194304ULL * 2);
  bf16_t* W2b   = (bf16_t*)oalloc(4194304ULL * 2);
  bf16_t* Wqb   = (bf16_t*)oalloc(262144ULL * 2);
  bf16_t* Wrpb  = (bf16_t*)oalloc(262144ULL * 2);
  bf16_t* Kb    = (bf16_t*)oalloc(28672ULL * 512 * 2);
  bf16_t* hb    = (bf16_t*)oalloc(4096ULL * 2048 * 2);
  bf16_t* scb   = (bf16_t*)oalloc(4096ULL * 28672 * 2);

  // survivors in d_ws
  bf16_t* tokb = (bf16_t*)walloc(16384000ULL * 2);
  float*  x    = (float*)walloc(4096ULL * 512 * 4);
  bf16_t* xb   = (bf16_t*)walloc(4096ULL * 512 * 2);
  bf16_t* qh   = (bf16_t*)walloc(2097152ULL * 2);
  bf16_t* kh   = (bf16_t*)walloc(2097152ULL * 2);
  bf16_t* vt   = (bf16_t*)walloc(2097152ULL * 2);
  bf16_t* attob = (bf16_t*)walloc(4096ULL * 512 * 2);
  bf16_t* qmb  = (bf16_t*)walloc(4096ULL * 512 * 2);
  bf16_t* readb = (bf16_t*)walloc(4096ULL * 512 * 2);
  float*  tval = (float*)walloc(3ULL * 4096 * 4 * 4);
  int*    tidx = (int*)walloc(3ULL * 4096 * 4 * 4);
  bf16_t* xfb  = (bf16_t*)walloc(4096ULL * 512 * 2);

  // all f32->bf16 conversions in one launch
  F2BArgs fa;
  fa.s[0] = tok;  fa.d[0] = tokb;  fa.n4[0] = 4096000;
  fa.s[1] = Wqkv; fa.d[1] = Wqkvb; fa.n4[1] = 786432;
  fa.s[2] = Wo;   fa.d[2] = Wob;   fa.n4[2] = 262144;
  fa.s[3] = W1;   fa.d[3] = W1b;   fa.n4[3] = 1048576;
  fa.s[4] = W2;   fa.d[4] = W2b;   fa.n4[4] = 1048576;
  fa.s[5] = Wq;   fa.d[5] = Wqb;   fa.n4[5] = 65536;
  fa.s[6] = Wrp;  fa.d[6] = Wrpb;  fa.n4[6] = 65536;
  fa.s[7] = K0;   fa.d[7] = Kb;                fa.n4[7] = 2097152;
  fa.s[8] = K1;   fa.d[8] = Kb + 8388608L;     fa.n4[8] = 1048576;
  fa.s[9] = K2;   fa.d[9] = Kb + 12582912L;    fa.n4[9] = 524288;
  k_f2b_all<<<dim3(128, 10), 256, 0, stream>>>(fa);

  k_embed<<<4096, 256, 0, stream>>>(ids, tok, pos, x, xb);

  for (int i = 0; i < 4; ++i) {
    k_gemm_bt<bf16_t, true, 1><<<dim3(12, 32), 256, 0, stream>>>(
        xb, 512, Wqkvb + (long long)i * 786432, 512, (bf16_t*)nullptr, 0,
        bqkv + i * 1536, 512, 1.0f, qh, kh, vt);
    k_flash<<<dim3(16, 16), 256, 0, stream>>>(qh, kh, vt, attob);
    // Wo GEMM + residual + ln1 fused
    k_gemm_ln<1><<<256, 512, 0, stream>>>(
        attob, 512, Wob + (long long)i * 262144, 512, 512, bo + i * 512, x,
        ln1s + i * 512, ln1b + i * 512, x, xb, 1.0f);
    // W1 GEMM + gelu fused
    k_gemm_bt<bf16_t, true, 2><<<dim3(16, 32), 256, 0, stream>>>(
        xb, 512, W1b + (long long)i * 1048576, 512, hb, 2048,
        b1 + i * 2048, 512, 1.0f, nullptr, nullptr, nullptr);
    // W2 GEMM + residual + ln2 fused
    k_gemm_ln<1><<<256, 512, 0, stream>>>(
        hb, 2048, W2b + (long long)i * 1048576, 2048, 2048, b2 + i * 512, x,
        ln2s + i * 512, ln2b + i * 512, x, xb, 1.0f);
  }

  // memory path: qm = (x@Wq^T + bq)/sqrt(512) in bf16
  k_gemm_ln<0><<<256, 512, 0, stream>>>(
      xb, 512, Wqb, 512, 512, bq, nullptr, nullptr, nullptr, nullptr, qmb,
      0.044194173824159216f);
  // one score GEMM over concatenated banks: [4096, 28672]
  k_gemm256<bf16_t><<<dim3(112, 16), 512, 0, stream>>>(
      qmb, 512, Kb, 512, scb, 28672, 512, 1.0f);
  TopkArgs ta; ta.sal0 = s0; ta.sal1 = s1; ta.sal2 = s2;
  k_topk<<<dim3(1024, 3), 256, 0, stream>>>(scb, ta, tval, tidx);
  k_read<<<4096, 256, 0, stream>>>(tval, tidx, V0, V1, V2, readb);
  // Wrp GEMM + residual + lnout fused (writes xfb only)
  k_gemm_ln<2><<<256, 512, 0, stream>>>(
      readb, 512, Wrpb, 512, 512, brp, x, lnos, lnob, nullptr, xfb, 1.0f);
  // logits = x @ tok_embed^T  (f32, overwrites all d_out scratch)
  k_gemm256<float><<<dim3(125, 16), 512, 0, stream>>>(
      xfb, 512, tokb, 512, (float*)d_out, 32000, 512, 1.0f);
}

// Round 5
// 1366.709 us; speedup vs baseline: 1.1596x; 1.1596x over previous
//
#include <hip/hip_runtime.h>
#include <cstdint>

typedef __bf16 bf16_t;
typedef __bf16 bf16x2 __attribute__((ext_vector_type(2)));
typedef __bf16 bf16x4 __attribute__((ext_vector_type(4)));
typedef __bf16 bf16x8 __attribute__((ext_vector_type(8)));
typedef float f32x4 __attribute__((ext_vector_type(4)));
typedef unsigned short u16;
typedef unsigned int u32;

#define DEVI static __device__ __forceinline__

// async global->LDS, 16B per lane; LDS dest = wave-uniform base + lane*16
DEVI void g2l16(const void* g, void* l) {
  __builtin_amdgcn_global_load_lds((__attribute__((address_space(1))) void*)g,
                                   (__attribute__((address_space(3))) void*)l,
                                   16, 0, 0);
}

// ---------------- fused f32 -> bf16 convert (all tensors, one launch) ----------------
struct F2BArgs {
  const float* s[10];
  bf16_t* d[10];
  int n4[10];
};
__global__ void k_f2b_all(F2BArgs a) {
  const int seg = blockIdx.y;
  const float* __restrict__ in = a.s[seg];
  bf16_t* __restrict__ out = a.d[seg];
  const long n4 = a.n4[seg];
  const long stride = (long)gridDim.x * blockDim.x;
  for (long i = (long)blockIdx.x * blockDim.x + threadIdx.x; i < n4; i += stride) {
    float4 v = ((const float4*)in)[i];
    bf16x4 o = {(bf16_t)v.x, (bf16_t)v.y, (bf16_t)v.z, (bf16_t)v.w};
    ((bf16x4*)out)[i] = o;
  }
}

// ---------------- embedding ----------------
__global__ void k_embed(const int* __restrict__ ids, const float* __restrict__ tok,
                        const float* __restrict__ pos, float* __restrict__ x,
                        bf16_t* __restrict__ xb) {
  int r = blockIdx.x;
  int t = r & 2047;
  long id = ids[r];
  int d = threadIdx.x * 2;
  float2 a = *(const float2*)(tok + id * 512 + d);
  float2 p = *(const float2*)(pos + (long)t * 512 + d);
  float o0 = a.x + p.x, o1 = a.y + p.y;
  *(float2*)(x + (long)r * 512 + d) = make_float2(o0, o1);
  bf16x2 ob = {(bf16_t)o0, (bf16_t)o1};
  *(bf16x2*)(xb + (long)r * 512 + d) = ob;
}

DEVI float gelu_f(float f) {
  return 0.5f * f * (1.0f + erff(f * 0.70710678118654752f));
}

// ---------------- 128x128 GEMM: C[M,N] = (A[M,K] @ B[N,K]^T + bias) * alpha ----------------
// EPI: 1 = qkv split (q*0.125->qh, k->kh, v->vt), 2 = gelu -> C(bf16)
template <typename CT, bool BIAS, int EPI>
__global__ __launch_bounds__(256, 2) void k_gemm_bt(
    const bf16_t* __restrict__ A, int lda, const bf16_t* __restrict__ B, int ldb,
    CT* __restrict__ C, int ldc, const float* __restrict__ bias, int K, float alpha,
    bf16_t* __restrict__ qh, bf16_t* __restrict__ kh, bf16_t* __restrict__ vt) {
  __shared__ bf16_t As[4096];  // [128][32]
  __shared__ bf16_t Bs[4096];  // [128][32]
  const int tid = threadIdx.x;
  const int lane = tid & 63;
  const int w = tid >> 6;
  const int wm = w >> 1, wn = w & 1;
  const int m0 = blockIdx.y * 128;
  const int n0 = blockIdx.x * 128;

  f32x4 acc[4][4];
#pragma unroll
  for (int m = 0; m < 4; ++m)
#pragma unroll
    for (int n = 0; n < 4; ++n) acc[m][n] = (f32x4){0.f, 0.f, 0.f, 0.f};

  const int srow = tid >> 2;
  const int scol = (tid & 3) * 8;
  const int fr = lane & 15;
  const int g4 = lane >> 4;
  const int kg = g4 * 8;

  for (int k0 = 0; k0 < K; k0 += 32) {
#pragma unroll
    for (int p = 0; p < 2; ++p) {
      g2l16(A + (long long)(m0 + p * 64 + srow) * lda + (k0 + scol), As + p * 2048 + w * 512);
      g2l16(B + (long long)(n0 + p * 64 + srow) * ldb + (k0 + scol), Bs + p * 2048 + w * 512);
    }
    __syncthreads();
    bf16x8 fa[4], fb[4];
#pragma unroll
    for (int m = 0; m < 4; ++m)
      fa[m] = *(const bf16x8*)(As + (wm * 64 + m * 16 + fr) * 32 + kg);
#pragma unroll
    for (int n = 0; n < 4; ++n)
      fb[n] = *(const bf16x8*)(Bs + (wn * 64 + n * 16 + fr) * 32 + kg);
#pragma unroll
    for (int m = 0; m < 4; ++m)
#pragma unroll
      for (int n = 0; n < 4; ++n)
        acc[m][n] = __builtin_amdgcn_mfma_f32_16x16x32_bf16(fa[m], fb[n], acc[m][n], 0, 0, 0);
    __syncthreads();
  }

#pragma unroll
  for (int n = 0; n < 4; ++n) {
    const int col = n0 + wn * 64 + n * 16 + fr;
    const float bv = BIAS ? bias[col] : 0.0f;
    if (EPI == 1) {
      const int reg = col >> 9;
      const int h = (col >> 6) & 7;
      const int hd = col & 63;
#pragma unroll
      for (int m = 0; m < 4; ++m) {
        const int rb = m0 + wm * 64 + m * 16 + g4 * 4;
#pragma unroll
        for (int r = 0; r < 4; ++r) {
          const int row = rb + r;
          const int b = row >> 11, t = row & 2047;
          const long long bh = (long long)b * 8 + h;
          float v = acc[m][n][r] + bv;
          if (reg == 0) qh[(bh * 2048 + t) * 64 + hd] = (bf16_t)(v * 0.125f);
          else if (reg == 1) kh[(bh * 2048 + t) * 64 + hd] = (bf16_t)v;
          else vt[(bh * 64 + hd) * 2048 + t] = (bf16_t)v;
        }
      }
    } else {
#pragma unroll
      for (int m = 0; m < 4; ++m) {
        const long long rb = m0 + wm * 64 + m * 16 + g4 * 4;
#pragma unroll
        for (int r = 0; r < 4; ++r) {
          float v = (acc[m][n][r] + bv) * alpha;
          if (EPI == 2) v = gelu_f(v);
          C[(rb + r) * (long long)ldc + col] = (CT)v;
        }
      }
    }
  }
}

// ---------------- 64x128 GEMM (for small-N shapes; full-CU grids) ----------------
template <typename CT, bool BIAS>
__global__ __launch_bounds__(256, 4) void k_gemm64(
    const bf16_t* __restrict__ A, int lda, const bf16_t* __restrict__ B, int ldb,
    CT* __restrict__ C, int ldc, const float* __restrict__ bias, int K, float alpha) {
  __shared__ bf16_t As[64 * 32];
  __shared__ bf16_t Bs[128 * 32];
  const int tid = threadIdx.x;
  const int lane = tid & 63;
  const int w = tid >> 6;
  const int wm = w >> 1, wn = w & 1;
  const int m0 = blockIdx.y * 64;
  const int n0 = blockIdx.x * 128;

  f32x4 acc[2][4];
#pragma unroll
  for (int m = 0; m < 2; ++m)
#pragma unroll
    for (int n = 0; n < 4; ++n) acc[m][n] = (f32x4){0.f, 0.f, 0.f, 0.f};

  const int srow = tid >> 2;
  const int scol = (tid & 3) * 8;
  const int fr = lane & 15;
  const int g4 = lane >> 4;
  const int kg = g4 * 8;

  for (int k0 = 0; k0 < K; k0 += 32) {
    g2l16(A + (long long)(m0 + srow) * lda + (k0 + scol), As + tid * 8);
    g2l16(B + (long long)(n0 + srow) * ldb + (k0 + scol), Bs + tid * 8);
    g2l16(B + (long long)(n0 + 64 + srow) * ldb + (k0 + scol), Bs + 2048 + tid * 8);
    __syncthreads();
    bf16x8 fa[2], fb[4];
#pragma unroll
    for (int m = 0; m < 2; ++m)
      fa[m] = *(const bf16x8*)(As + (wm * 32 + m * 16 + fr) * 32 + kg);
#pragma unroll
    for (int n = 0; n < 4; ++n)
      fb[n] = *(const bf16x8*)(Bs + (wn * 64 + n * 16 + fr) * 32 + kg);
#pragma unroll
    for (int m = 0; m < 2; ++m)
#pragma unroll
      for (int n = 0; n < 4; ++n)
        acc[m][n] = __builtin_amdgcn_mfma_f32_16x16x32_bf16(fa[m], fb[n], acc[m][n], 0, 0, 0);
    __syncthreads();
  }

#pragma unroll
  for (int n = 0; n < 4; ++n) {
    const int col = n0 + wn * 64 + n * 16 + fr;
    const float bv = BIAS ? bias[col] : 0.0f;
#pragma unroll
    for (int m = 0; m < 2; ++m) {
      const long long rb = m0 + wm * 32 + m * 16 + g4 * 4;
#pragma unroll
      for (int r = 0; r < 4; ++r)
        C[(rb + r) * (long long)ldc + col] = (CT)((acc[m][n][r] + bv) * alpha);
    }
  }
}

// ---------------- 256x256 GEMM, BK=64, 8 waves, counted-vmcnt 2-phase pipeline ----------------
// EPI 0: C store (CT, *alpha). EPI 1: score epilogue — add per-col salience, store bf16
// score to C AND per-64-col chunk-max (bf16) to cmax[M][448].
// Block mapping: XCD-chunked, m-fastest (all 16 m-tiles of an N-panel in one XCD chunk
// so the B panel is HBM-fetched once and L2-served; A becomes L2-resident per XCD).
template <typename CT, int EPI>
__global__ __launch_bounds__(512, 2) void k_gemm256(
    const bf16_t* __restrict__ A, int lda, const bf16_t* __restrict__ B, int ldb,
    CT* __restrict__ C, int ldc, int K, float alpha,
    const float* __restrict__ s0, const float* __restrict__ s1,
    const float* __restrict__ s2, bf16_t* __restrict__ cmax) {
  __shared__ char lds[131072];
  const int tid = threadIdx.x;
  const int lane = tid & 63;
  const int w = tid >> 6;
  const int wm = w >> 2, wn = w & 3;
  const int fr = lane & 15;
  const int g4 = lane >> 4;

  const int ny = gridDim.y;
  const int nwg = gridDim.x * ny;
  int orig = blockIdx.y * gridDim.x + blockIdx.x;
  int lin = ((nwg & 7) == 0) ? ((orig & 7) * (nwg >> 3) + (orig >> 3)) : orig;
  const int m0 = (lin % ny) * 256;
  const int n0 = (lin / ny) * 256;

  f32x4 acc[8][4];
#pragma unroll
  for (int m = 0; m < 8; ++m)
#pragma unroll
    for (int n = 0; n < 4; ++n) acc[m][n] = (f32x4){0.f, 0.f, 0.f, 0.f};

  const int sr = tid >> 2;
  const int sc = (tid & 3) * 16;
  const int NT = K >> 6;

  auto stage = [&](int t, int p, int buf) {
    const long long kb = (long long)t * 128 + p * 64;
    char* ab = (char*)lds + buf * 65536 + p * 16384;
    char* bb = ab + 32768;
    const int sw = (sr & 3) << 4;
    g2l16((const char*)A + (long long)(m0 + sr) * (lda * 2) + kb + (sc ^ sw), ab + tid * 16);
    g2l16((const char*)A + (long long)(m0 + 128 + sr) * (lda * 2) + kb + (sc ^ sw),
          ab + (tid + 512) * 16);
    g2l16((const char*)B + (long long)(n0 + sr) * (ldb * 2) + kb + (sc ^ sw), bb + tid * 16);
    g2l16((const char*)B + (long long)(n0 + 128 + sr) * (ldb * 2) + kb + (sc ^ sw),
          bb + (tid + 512) * 16);
  };

  stage(0, 0, 0);
  stage(0, 1, 0);
  asm volatile("s_waitcnt vmcnt(4)" ::: "memory");
  __builtin_amdgcn_s_barrier();
  __builtin_amdgcn_sched_barrier(0);

  int cur = 0;
  for (int t = 0; t < NT; ++t) {
#pragma unroll
    for (int p = 0; p < 2; ++p) {
      const char* ab = (const char*)lds + cur * 65536 + p * 16384;
      const char* bb = ab + 32768;
      bf16x8 fa[8], fb[4];
#pragma unroll
      for (int m = 0; m < 8; ++m) {
        const int row = wm * 128 + m * 16 + fr;
        fa[m] = *(const bf16x8*)(ab + row * 64 + ((g4 * 16) ^ ((row & 3) << 4)));
      }
#pragma unroll
      for (int n = 0; n < 4; ++n) {
        const int row = wn * 64 + n * 16 + fr;
        fb[n] = *(const bf16x8*)(bb + row * 64 + ((g4 * 16) ^ ((row & 3) << 4)));
      }
      if (t + 1 < NT) stage(t + 1, p, cur ^ 1);
      if (t == NT - 1 && p == 0) {
        asm volatile("s_waitcnt vmcnt(0)" ::: "memory");
      } else {
        asm volatile("s_waitcnt vmcnt(4)" ::: "memory");
      }
      __builtin_amdgcn_s_barrier();
      __builtin_amdgcn_sched_barrier(0);
      __builtin_amdgcn_s_setprio(1);
#pragma unroll
      for (int m = 0; m < 8; ++m)
#pragma unroll
        for (int n = 0; n < 4; ++n)
          acc[m][n] = __builtin_amdgcn_mfma_f32_16x16x32_bf16(fa[m], fb[n], acc[m][n], 0, 0, 0);
      __builtin_amdgcn_s_setprio(0);
    }
    cur ^= 1;
  }

  if (EPI == 0) {
#pragma unroll
    for (int n = 0; n < 4; ++n) {
      const int col = n0 + wn * 64 + n * 16 + fr;
#pragma unroll
      for (int m = 0; m < 8; ++m) {
        const long long rb = m0 + wm * 128 + m * 16 + g4 * 4;
#pragma unroll
        for (int r = 0; r < 4; ++r)
          C[(rb + r) * (long long)ldc + col] = (CT)(acc[m][n][r] * alpha);
      }
    }
  } else {
    // salience for this block's level (tiles never straddle level boundaries)
    const float* salp;
    int coff;
    if (n0 < 16384) { salp = s0; coff = 0; }
    else if (n0 < 24576) { salp = s1; coff = 16384; }
    else { salp = s2; coff = 24576; }
    float bv[4];
    int col[4];
#pragma unroll
    for (int n = 0; n < 4; ++n) {
      col[n] = n0 + wn * 64 + n * 16 + fr;
      bv[n] = salp[col[n] - coff];
    }
    bf16_t* crow = (bf16_t*)C;
    const int chk = (n0 >> 6) + wn;
#pragma unroll
    for (int m = 0; m < 8; ++m) {
#pragma unroll
      for (int r = 0; r < 4; ++r) {
        const long long row = m0 + wm * 128 + m * 16 + g4 * 4 + r;
        float v0 = acc[m][0][r] + bv[0];
        float v1 = acc[m][1][r] + bv[1];
        float v2 = acc[m][2][r] + bv[2];
        float v3 = acc[m][3][r] + bv[3];
        float rm = fmaxf(fmaxf(v0, v1), fmaxf(v2, v3));
        rm = fmaxf(rm, __shfl_xor(rm, 1));
        rm = fmaxf(rm, __shfl_xor(rm, 2));
        rm = fmaxf(rm, __shfl_xor(rm, 4));
        rm = fmaxf(rm, __shfl_xor(rm, 8));
        crow[row * (long long)ldc + col[0]] = (bf16_t)v0;
        crow[row * (long long)ldc + col[1]] = (bf16_t)v1;
        crow[row * (long long)ldc + col[2]] = (bf16_t)v2;
        crow[row * (long long)ldc + col[3]] = (bf16_t)v3;
        if (fr == 0) cmax[row * 448 + chk] = (bf16_t)rm;
      }
    }
  }
}

// ---------------- fused flash attention ----------------
__global__ __launch_bounds__(256, 2) void k_flash(
    const bf16_t* __restrict__ qh, const bf16_t* __restrict__ kh,
    const bf16_t* __restrict__ vt, bf16_t* __restrict__ out) {
  __shared__ bf16_t Ks[128 * 64];
  __shared__ bf16_t Vs[64 * 128];
  __shared__ bf16_t Ps[4 * 32 * 128];
  const int tid = threadIdx.x;
  const int lane = tid & 63;
  const int w = tid >> 6;
  const int bh = blockIdx.y;
  const int q0 = blockIdx.x * 128;
  const int fr = lane & 15;
  const int g4 = lane >> 4;
  const int kg = g4 * 8;

  bf16x8 qf[2][2];
  {
    const bf16_t* qb = qh + ((long long)bh * 2048 + q0 + w * 32) * 64;
#pragma unroll
    for (int m = 0; m < 2; ++m)
#pragma unroll
      for (int ks = 0; ks < 2; ++ks)
        qf[m][ks] = *(const bf16x8*)(qb + (m * 16 + fr) * 64 + ks * 32 + kg);
  }

  f32x4 oacc[2][4];
#pragma unroll
  for (int m = 0; m < 2; ++m)
#pragma unroll
    for (int n = 0; n < 4; ++n) oacc[m][n] = (f32x4){0.f, 0.f, 0.f, 0.f};
  float mi[8], li[8];
#pragma unroll
  for (int j = 0; j < 8; ++j) { mi[j] = -1e30f; li[j] = 0.f; }

  char* PsW = (char*)(Ps + w * 32 * 128);
  const bf16_t* kbase = kh + (long long)bh * 2048 * 64;
  const bf16_t* vbase = vt + (long long)bh * 64 * 2048;

  for (int kt = 0; kt < 16; ++kt) {
#pragma unroll
    for (int i = 0; i < 4; ++i) {
      int row = (w * 4 + i) * 8 + (lane >> 3);
      int c = lane & 7;
      g2l16(kbase + ((long long)(kt * 128 + row)) * 64 + (c ^ (row & 7)) * 8,
            Ks + (w * 4 + i) * 512);
    }
#pragma unroll
    for (int i = 0; i < 4; ++i) {
      int d = w * 16 + i * 4 + (lane >> 4);
      int c = lane & 15;
      g2l16(vbase + (long long)d * 2048 + kt * 128 + ((c ^ (d & 7)) * 8),
            Vs + (w * 16 + i * 4) * 128);
    }
    __syncthreads();

    f32x4 s[2][8];
#pragma unroll
    for (int m = 0; m < 2; ++m)
#pragma unroll
      for (int n = 0; n < 8; ++n) s[m][n] = (f32x4){0.f, 0.f, 0.f, 0.f};
#pragma unroll
    for (int ks = 0; ks < 2; ++ks) {
#pragma unroll
      for (int n = 0; n < 8; ++n) {
        int row = n * 16 + fr;
        bf16x8 kf = *(const bf16x8*)((const char*)Ks + row * 128 +
                                     ((ks * 64 + kg * 2) ^ ((row & 7) << 4)));
#pragma unroll
        for (int m = 0; m < 2; ++m)
          s[m][n] = __builtin_amdgcn_mfma_f32_16x16x32_bf16(qf[m][ks], kf, s[m][n], 0, 0, 0);
      }
    }

#pragma unroll
    for (int m = 0; m < 2; ++m) {
#pragma unroll
      for (int r = 0; r < 4; ++r) {
        float pm = -1e30f;
#pragma unroll
        for (int n = 0; n < 8; ++n) pm = fmaxf(pm, s[m][n][r]);
        pm = fmaxf(pm, __shfl_xor(pm, 1));
        pm = fmaxf(pm, __shfl_xor(pm, 2));
        pm = fmaxf(pm, __shfl_xor(pm, 4));
        pm = fmaxf(pm, __shfl_xor(pm, 8));
        const int ri = m * 4 + r;
        const float mnew = fmaxf(mi[ri], pm);
        const float alpha = __expf(mi[ri] - mnew);
        mi[ri] = mnew;
        const int lr = m * 16 + g4 * 4 + r;
        const int sw = (lr & 7) << 4;
        float rs = 0.f;
#pragma unroll
        for (int n = 0; n < 8; ++n) {
          float p = __expf(s[m][n][r] - mnew);
          rs += p;
          *(bf16_t*)(PsW + lr * 256 + (((n * 16 + fr) * 2) ^ sw)) = (bf16_t)p;
        }
        rs += __shfl_xor(rs, 1);
        rs += __shfl_xor(rs, 2);
        rs += __shfl_xor(rs, 4);
        rs += __shfl_xor(rs, 8);
        li[ri] = li[ri] * alpha + rs;
#pragma unroll
        for (int n = 0; n < 4; ++n) oacc[m][n][r] *= alpha;
      }
    }

#pragma unroll
    for (int ks = 0; ks < 4; ++ks) {
      bf16x8 pa[2];
#pragma unroll
      for (int m = 0; m < 2; ++m) {
        int row = m * 16 + fr;
        pa[m] = *(const bf16x8*)(PsW + row * 256 + ((ks * 64 + kg * 2) ^ ((row & 7) << 4)));
      }
#pragma unroll
      for (int n = 0; n < 4; ++n) {
        int d = n * 16 + fr;
        bf16x8 vf = *(const bf16x8*)((const char*)Vs + d * 256 +
                                     ((ks * 64 + kg * 2) ^ ((d & 7) << 4)));
#pragma unroll
        for (int m = 0; m < 2; ++m)
          oacc[m][n] = __builtin_amdgcn_mfma_f32_16x16x32_bf16(pa[m], vf, oacc[m][n], 0, 0, 0);
      }
    }
    __syncthreads();
  }

  const int b = bh >> 3, h = bh & 7;
  bf16_t* ob = out + ((long long)b * 2048 + q0 + w * 32) * 512 + h * 64;
#pragma unroll
  for (int m = 0; m < 2; ++m)
#pragma unroll
    for (int r = 0; r < 4; ++r) {
      float inv = 1.0f / li[m * 4 + r];
#pragma unroll
      for (int n = 0; n < 4; ++n)
        ob[(m * 16 + g4 * 4 + r) * 512 + n * 16 + fr] = (bf16_t)(oacc[m][n][r] * inv);
    }
}

// ---------------- LN(xin + delta) * s + b -> xout (f32) + xbf (bf16), D=512 ----------------
__global__ void k_ln(const float* __restrict__ xin, const float* __restrict__ delta,
                     const float* __restrict__ s, const float* __restrict__ b,
                     float* __restrict__ xout, bf16_t* __restrict__ xbf) {
  __shared__ float red[8];
  const int r = blockIdx.x;
  const int tid = threadIdx.x;
  const int d = tid * 2;
  const int lane = tid & 63, w = tid >> 6;
  float2 xi = *(const float2*)(xin + (long)r * 512 + d);
  float2 de = *(const float2*)(delta + (long)r * 512 + d);
  float y0 = xi.x + de.x, y1 = xi.y + de.y;
  float sum = y0 + y1, ss = y0 * y0 + y1 * y1;
#pragma unroll
  for (int o = 32; o > 0; o >>= 1) { sum += __shfl_xor(sum, o); ss += __shfl_xor(ss, o); }
  if (lane == 0) { red[w] = sum; red[4 + w] = ss; }
  __syncthreads();
  sum = red[0] + red[1] + red[2] + red[3];
  ss = red[4] + red[5] + red[6] + red[7];
  const float mean = sum * (1.0f / 512.0f);
  const float var = ss * (1.0f / 512.0f) - mean * mean;
  const float rstd = rsqrtf(var + 1e-5f);
  float o0 = (y0 - mean) * rstd * s[d] + b[d];
  float o1 = (y1 - mean) * rstd * s[d + 1] + b[d + 1];
  *(float2*)(xout + (long)r * 512 + d) = make_float2(o0, o1);
  bf16x2 ob = {(bf16_t)o0, (bf16_t)o1};
  *(bf16x2*)(xbf + (long)r * 512 + d) = ob;
}

// ---------------- chunk-max filtered top-4 merge ----------------
// One wave per row. Per level: m4 = 4th-largest 64-col chunk max (over-kill on ties is
// safe), rescan chunks with max >= m4 using packed u32 keys (bf16-key<<15 | (0x7fff-idx))
// which reproduces value-desc, then lower-index ordering exactly.
DEVI void tki4(u32* k, u32 nk) {
  if (nk <= k[3]) return;
  k[3] = nk;
  if (k[3] > k[2]) { u32 t = k[2]; k[2] = k[3]; k[3] = t; }
  if (k[2] > k[1]) { u32 t = k[1]; k[1] = k[2]; k[2] = t; }
  if (k[1] > k[0]) { u32 t = k[0]; k[0] = k[1]; k[1] = t; }
}
__global__ void k_topk_merge(const u16* __restrict__ scb, const bf16_t* __restrict__ cmax,
                             float* __restrict__ tv, int* __restrict__ ti) {
  const int r = blockIdx.x * 4 + (threadIdx.x >> 6);
  const int lane = threadIdx.x & 63;
  const float NINF = -3.0e38f;
  for (int lev = 0; lev < 3; ++lev) {
    const int cbase = lev == 0 ? 0 : (lev == 1 ? 256 : 384);
    const int nc = lev == 0 ? 4 : (lev == 1 ? 2 : 1);  // chunk-slots per lane
    const int coff = cbase << 6;
    float cm[4], work[4];
#pragma unroll
    for (int j = 0; j < 4; ++j) {
      cm[j] = (j < nc) ? (float)cmax[(long)r * 448 + cbase + j * 64 + lane] : NINF;
      work[j] = cm[j];
    }
    float m4 = NINF;
#pragma unroll
    for (int e = 0; e < 4; ++e) {
      float mx = fmaxf(fmaxf(work[0], work[1]), fmaxf(work[2], work[3]));
#pragma unroll
      for (int dd = 1; dd < 64; dd <<= 1) mx = fmaxf(mx, __shfl_xor(mx, dd));
#pragma unroll
      for (int j = 0; j < 4; ++j)
        if (work[j] == mx) work[j] = NINF;
      m4 = mx;
    }
    u32 rk[4] = {0u, 0u, 0u, 0u};
    for (int j = 0; j < nc; ++j) {
      unsigned long long bal = __ballot(cm[j] >= m4);
      while (bal) {
        int c = __ffsll(bal) - 1;
        bal &= bal - 1;
        const int chunk = cbase + j * 64 + c;
        u16 sb = scb[(long)r * 28672 + chunk * 64 + lane];
        u32 k16 = (sb & 0x8000) ? (u32)((~sb) & 0xFFFF) : (u32)(sb | 0x8000);
        const int lidx = chunk * 64 + lane - coff;
        tki4(rk, (k16 << 15) | (u32)(0x7FFF - lidx));
      }
    }
#pragma unroll
    for (int dd = 1; dd < 64; dd <<= 1) {
      u32 o[4];
#pragma unroll
      for (int j = 0; j < 4; ++j) o[j] = (u32)__shfl_xor((int)rk[j], dd);
#pragma unroll
      for (int j = 0; j < 4; ++j) tki4(rk, o[j]);
    }
    if (lane == 0) {
      const long o = ((long)lev * 4096 + r) * 4;
#pragma unroll
      for (int j = 0; j < 4; ++j) {
        u32 k16 = rk[j] >> 15;
        u16 b = (k16 & 0x8000) ? (u16)(k16 ^ 0x8000) : (u16)(~k16);
        u32 fb = ((u32)b) << 16;
        tv[o + j] = __uint_as_float(fb);
        ti[o + j] = 0x7FFF - (int)(rk[j] & 0x7FFF);
      }
    }
  }
}

// ---------------- gather V by top-4, softmax weights, avg over 3 levels ----------------
__global__ void k_read(const float* __restrict__ tv, const int* __restrict__ ti,
                       const float* __restrict__ V0, const float* __restrict__ V1,
                       const float* __restrict__ V2, bf16_t* __restrict__ readb) {
  const int r = blockIdx.x;
  const int d = threadIdx.x * 2;
  float a0 = 0.f, a1 = 0.f;
  const float* Vs[3] = {V0, V1, V2};
#pragma unroll
  for (int lev = 0; lev < 3; ++lev) {
    const float* tvr = tv + ((long)lev * 4096 + r) * 4;
    const int* tir = ti + ((long)lev * 4096 + r) * 4;
    float t0 = tvr[0], t1 = tvr[1], t2 = tvr[2], t3 = tvr[3];
    float m = fmaxf(fmaxf(t0, t1), fmaxf(t2, t3));
    float e0 = __expf(t0 - m), e1 = __expf(t1 - m), e2 = __expf(t2 - m), e3 = __expf(t3 - m);
    float inv = 1.0f / (e0 + e1 + e2 + e3);
    float w4[4] = {e0 * inv, e1 * inv, e2 * inv, e3 * inv};
#pragma unroll
    for (int k = 0; k < 4; ++k) {
      const float* vr = Vs[lev] + (long)tir[k] * 512;
      a0 += w4[k] * vr[d];
      a1 += w4[k] * vr[d + 1];
    }
  }
  bf16x2 o = {(bf16_t)(a0 * (1.0f / 3.0f)), (bf16_t)(a1 * (1.0f / 3.0f))};
  *(bf16x2*)(readb + (long)r * 512 + d) = o;
}

// ---------------- host ----------------
extern "C" void kernel_launch(void* const* d_in, const int* in_sizes, int n_in,
                              void* d_out, int out_size, void* d_ws, size_t ws_size,
                              hipStream_t stream) {
  (void)in_sizes; (void)n_in; (void)out_size; (void)ws_size;
  const int* ids = (const int*)d_in[0];
  const float* tok = (const float*)d_in[1];
  const float* pos = (const float*)d_in[2];
  const float* Wqkv = (const float*)d_in[3];
  const float* bqkv = (const float*)d_in[4];
  const float* Wo = (const float*)d_in[5];
  const float* bo = (const float*)d_in[6];
  const float* ln1s = (const float*)d_in[7];
  const float* ln1b = (const float*)d_in[8];
  const float* W1 = (const float*)d_in[9];
  const float* b1 = (const float*)d_in[10];
  const float* W2 = (const float*)d_in[11];
  const float* b2 = (const float*)d_in[12];
  const float* ln2s = (const float*)d_in[13];
  const float* ln2b = (const float*)d_in[14];
  const float* Wq = (const float*)d_in[15];
  const float* bq = (const float*)d_in[16];
  const float* Wrp = (const float*)d_in[17];
  const float* brp = (const float*)d_in[18];
  const float* lnos = (const float*)d_in[19];
  const float* lnob = (const float*)d_in[20];
  const float* K0 = (const float*)d_in[21];
  const float* V0 = (const float*)d_in[22];
  const float* s0 = (const float*)d_in[23];
  const float* K1 = (const float*)d_in[24];
  const float* V1 = (const float*)d_in[25];
  const float* s1 = (const float*)d_in[26];
  const float* K2 = (const float*)d_in[27];
  const float* V2 = (const float*)d_in[28];
  const float* s2 = (const float*)d_in[29];

  char* wp = (char*)d_ws;
  auto walloc = [&](size_t bytes) -> char* {
    char* p = wp; wp += (bytes + 255) & ~(size_t)255; return p;
  };
  char* op = (char*)d_out;
  auto oalloc = [&](size_t bytes) -> char* {
    char* p = op; op += (bytes + 255) & ~(size_t)255; return p;
  };

  // transients in d_out (all reads complete before lm_head overwrites d_out)
  bf16_t* Wqkvb = (bf16_t*)oalloc(3145728ULL * 2);
  bf16_t* Wob   = (bf16_t*)oalloc(1048576ULL * 2);
  bf16_t* W1b   = (bf16_t*)oalloc(4194304ULL * 2);
  bf16_t* W2b   = (bf16_t*)oalloc(4194304ULL * 2);
  bf16_t* Wqb   = (bf16_t*)oalloc(262144ULL * 2);
  bf16_t* Wrpb  = (bf16_t*)oalloc(262144ULL * 2);
  bf16_t* Kb    = (bf16_t*)oalloc(28672ULL * 512 * 2);
  bf16_t* hb    = (bf16_t*)oalloc(4096ULL * 2048 * 2);
  bf16_t* scb   = (bf16_t*)oalloc(4096ULL * 28672 * 2);

  // survivors in d_ws
  bf16_t* tokb = (bf16_t*)walloc(16384000ULL * 2);
  float*  x    = (float*)walloc(4096ULL * 512 * 4);
  bf16_t* xb   = (bf16_t*)walloc(4096ULL * 512 * 2);
  bf16_t* qh   = (bf16_t*)walloc(2097152ULL * 2);
  bf16_t* kh   = (bf16_t*)walloc(2097152ULL * 2);
  bf16_t* vt   = (bf16_t*)walloc(2097152ULL * 2);
  bf16_t* attob = (bf16_t*)walloc(4096ULL * 512 * 2);
  float*  delta = (float*)walloc(4096ULL * 512 * 4);
  bf16_t* qmb  = (bf16_t*)walloc(4096ULL * 512 * 2);
  bf16_t* readb = (bf16_t*)walloc(4096ULL * 512 * 2);
  float*  tval = (float*)walloc(3ULL * 4096 * 4 * 4);
  int*    tidx = (int*)walloc(3ULL * 4096 * 4 * 4);
  bf16_t* xfb  = (bf16_t*)walloc(4096ULL * 512 * 2);
  bf16_t* cmax = (bf16_t*)walloc(4096ULL * 448 * 2);

  // all f32->bf16 conversions in one launch
  F2BArgs fa;
  fa.s[0] = tok;  fa.d[0] = tokb;  fa.n4[0] = 4096000;
  fa.s[1] = Wqkv; fa.d[1] = Wqkvb; fa.n4[1] = 786432;
  fa.s[2] = Wo;   fa.d[2] = Wob;   fa.n4[2] = 262144;
  fa.s[3] = W1;   fa.d[3] = W1b;   fa.n4[3] = 1048576;
  fa.s[4] = W2;   fa.d[4] = W2b;   fa.n4[4] = 1048576;
  fa.s[5] = Wq;   fa.d[5] = Wqb;   fa.n4[5] = 65536;
  fa.s[6] = Wrp;  fa.d[6] = Wrpb;  fa.n4[6] = 65536;
  fa.s[7] = K0;   fa.d[7] = Kb;                fa.n4[7] = 2097152;
  fa.s[8] = K1;   fa.d[8] = Kb + 8388608L;     fa.n4[8] = 1048576;
  fa.s[9] = K2;   fa.d[9] = Kb + 12582912L;    fa.n4[9] = 524288;
  k_f2b_all<<<dim3(128, 10), 256, 0, stream>>>(fa);

  k_embed<<<4096, 256, 0, stream>>>(ids, tok, pos, x, xb);

  for (int i = 0; i < 4; ++i) {
    k_gemm_bt<bf16_t, true, 1><<<dim3(12, 32), 256, 0, stream>>>(
        xb, 512, Wqkvb + (long long)i * 786432, 512, (bf16_t*)nullptr, 0,
        bqkv + i * 1536, 512, 1.0f, qh, kh, vt);
    k_flash<<<dim3(16, 16), 256, 0, stream>>>(qh, kh, vt, attob);
    k_gemm64<float, true><<<dim3(4, 64), 256, 0, stream>>>(
        attob, 512, Wob + (long long)i * 262144, 512, delta, 512, bo + i * 512, 512, 1.0f);
    k_ln<<<4096, 256, 0, stream>>>(x, delta, ln1s + i * 512, ln1b + i * 512, x, xb);
    k_gemm_bt<bf16_t, true, 2><<<dim3(16, 32), 256, 0, stream>>>(
        xb, 512, W1b + (long long)i * 1048576, 512, hb, 2048,
        b1 + i * 2048, 512, 1.0f, nullptr, nullptr, nullptr);
    k_gemm64<float, true><<<dim3(4, 64), 256, 0, stream>>>(
        hb, 2048, W2b + (long long)i * 1048576, 2048, delta, 512, b2 + i * 512, 2048, 1.0f);
    k_ln<<<4096, 256, 0, stream>>>(x, delta, ln2s + i * 512, ln2b + i * 512, x, xb);
  }

  // memory path: qm = (x@Wq^T + bq)/sqrt(512) in bf16
  k_gemm64<bf16_t, true><<<dim3(4, 64), 256, 0, stream>>>(
      xb, 512, Wqb, 512, qmb, 512, bq, 512, 0.044194173824159216f);
  // score GEMM over concatenated banks with fused salience + chunk-max epilogue
  k_gemm256<bf16_t, 1><<<dim3(112, 16), 512, 0, stream>>>(
      qmb, 512, Kb, 512, scb, 28672, 512, 1.0f, s0, s1, s2, cmax);
  k_topk_merge<<<1024, 256, 0, stream>>>((const u16*)scb, cmax, tval, tidx);
  k_read<<<4096, 256, 0, stream>>>(tval, tidx, V0, V1, V2, readb);
  k_gemm64<float, true><<<dim3(4, 64), 256, 0, stream>>>(
      readb, 512, Wrpb, 512, delta, 512, brp, 512, 1.0f);
  k_ln<<<4096, 256, 0, stream>>>(x, delta, lnos, lnob, x, xfb);
  // logits = x @ tok_embed^T  (f32, overwrites all d_out scratch)
  k_gemm256<float, 0><<<dim3(125, 16), 512, 0, stream>>>(
      xfb, 512, tokb, 512, (float*)d_out, 32000, 512, 1.0f,
      nullptr, nullptr, nullptr, nullptr);
}